// Round 1
// baseline (421.794 us; speedup 1.0000x reference)
//
#include <hip/hip_runtime.h>
#include <math.h>

#define B 64
#define Q 300
#define PARTS 6
#define D 256
#define NHEAD 8
#define DHEAD 32
#define FF 512
#define NLAYERS 2
#define NCLS 396
#define L_TOK 10   // PARTS + 4 image tokens

// ---------------------------------------------------------------------------
// K1: global average pool of feat0..3 over spatial dims -> pooled[B][4][D]
// one block per (scale, b, d) row; row is contiguous s*s floats.
// ---------------------------------------------------------------------------
__global__ __launch_bounds__(256) void pool_kernel(
    const float* __restrict__ f0, const float* __restrict__ f1,
    const float* __restrict__ f2, const float* __restrict__ f3,
    float* __restrict__ pooled)
{
    int bid = blockIdx.x;
    int scale = bid >> 14;          // 16384 rows per scale (B*D)
    int r = bid & 16383;
    int b = r >> 8;
    int d = r & 255;
    const float* src;
    int n;
    switch (scale) {
        case 0: src = f0; n = 96 * 96; break;
        case 1: src = f1; n = 48 * 48; break;
        case 2: src = f2; n = 24 * 24; break;
        default: src = f3; n = 12 * 12; break;
    }
    const float4* p4 = reinterpret_cast<const float4*>(src + ((size_t)b * D + d) * (size_t)n);
    int n4 = n >> 2;
    float s = 0.f;
    for (int i = threadIdx.x; i < n4; i += 256) {
        float4 v = p4[i];
        s += v.x + v.y + v.z + v.w;
    }
    for (int off = 32; off; off >>= 1) s += __shfl_down(s, off, 64);
    __shared__ float red[4];
    int wid = threadIdx.x >> 6;
    int lane = threadIdx.x & 63;
    if (lane == 0) red[wid] = s;
    __syncthreads();
    if (threadIdx.x == 0) {
        float t = red[0] + red[1] + red[2] + red[3];
        pooled[((size_t)b * 4 + scale) * D + d] = t / (float)n;
    }
}

// ---------------------------------------------------------------------------
// K2: img token projection: tokens[b][6+i][:] = pooled[b][i] @ W[i]^T + bias[i]
// one block per (b, i); thread t computes output element t.
// ---------------------------------------------------------------------------
__global__ __launch_bounds__(256) void img_proj_kernel(
    const float* __restrict__ pooled, const float* __restrict__ w,
    const float* __restrict__ bias, float* __restrict__ tokens)
{
    int blk = blockIdx.x;
    int b = blk >> 2;
    int i = blk & 3;
    int tid = threadIdx.x;
    __shared__ float row[D];
    row[tid] = pooled[((size_t)b * 4 + i) * D + tid];
    __syncthreads();
    const float4* w4 = reinterpret_cast<const float4*>(w + ((size_t)i * D + tid) * D);
    float acc = 0.f;
    #pragma unroll 8
    for (int k4 = 0; k4 < D / 4; k4++) {
        float4 wv = w4[k4];
        int k = k4 * 4;
        acc += wv.x * row[k] + wv.y * row[k + 1] + wv.z * row[k + 2] + wv.w * row[k + 3];
    }
    tokens[((size_t)b * L_TOK + 6 + i) * D + tid] = acc + bias[i * D + tid];
}

// ---------------------------------------------------------------------------
// K3: per-class masked mean pool over queries -> tokens[b][0..5][:],
// plus key-padding bias (0 valid / -1e30 invalid) -> biasL[b][0..9]
// one block per batch element, thread t owns feature dim t.
// ---------------------------------------------------------------------------
__global__ __launch_bounds__(256) void cls_pool_kernel(
    const float* __restrict__ pred, const float* __restrict__ hs,
    float* __restrict__ tokens, float* __restrict__ biasL)
{
    int b = blockIdx.x;
    int tid = threadIdx.x;
    __shared__ float maskL[Q * PARTS];   // 1800 floats
    __shared__ float countsL[PARTS];
    for (int i = tid; i < Q * PARTS; i += 256) {
        float x = pred[(size_t)b * Q * PARTS + i];
        float sg = 1.f / (1.f + expf(-x));
        maskL[i] = (sg > 0.3f) ? 1.f : 0.f;
    }
    __syncthreads();
    if (tid < PARTS) {
        float c = 0.f;
        for (int q = 0; q < Q; q++) c += maskL[q * PARTS + tid];
        countsL[tid] = c;
    }
    __syncthreads();
    float acc[PARTS] = {0.f, 0.f, 0.f, 0.f, 0.f, 0.f};
    const float* hsb = hs + (size_t)b * Q * D + tid;
    for (int q = 0; q < Q; q++) {
        float h = hsb[(size_t)q * D];
        #pragma unroll
        for (int p = 0; p < PARTS; p++) acc[p] += maskL[q * PARTS + p] * h;
    }
    bool anyv = false;
    #pragma unroll
    for (int p = 0; p < PARTS; p++) anyv = anyv || (countsL[p] > 0.f);
    #pragma unroll
    for (int p = 0; p < PARTS; p++) {
        float cm = acc[p] / fmaxf(countsL[p], 1.f);
        if (p == 0 && !anyv) cm = hs[(size_t)b * Q * D + tid];  // fallback hs[b,0,:]
        tokens[((size_t)b * L_TOK + p) * D + tid] = cm;
    }
    if (tid < L_TOK) {
        float bv = 0.f;
        if (tid < PARTS) {
            bool v = countsL[tid] > 0.f;
            if (tid == 0 && !anyv) v = true;
            bv = v ? 0.f : -1e30f;
        }
        biasL[b * L_TOK + tid] = bv;
    }
}

// ---------------------------------------------------------------------------
// K4: fused 2-layer post-norm transformer encoder + masked pool + classifier.
// one block (256 threads) per batch element. Activations live in LDS.
// ---------------------------------------------------------------------------
__device__ __forceinline__ void layer_norm_10x256(
    float* __restrict__ xr, float* __restrict__ xs,
    const float* __restrict__ w, const float* __restrict__ bsc,
    float* __restrict__ rowm, float* __restrict__ rowrs, int tid)
{
    int wid = tid >> 6, lane = tid & 63;
    for (int r = wid; r < L_TOK; r += 4) {
        float s = 0.f, s2 = 0.f;
        for (int j = lane; j < D; j += 64) {
            float v = xr[r * D + j];
            s += v; s2 += v * v;
        }
        for (int off = 32; off; off >>= 1) {
            s += __shfl_down(s, off, 64);
            s2 += __shfl_down(s2, off, 64);
        }
        if (lane == 0) {
            float m = s * (1.f / D);
            float var = s2 * (1.f / D) - m * m;
            rowm[r] = m;
            rowrs[r] = rsqrtf(fmaxf(var, 0.f) + 1e-5f);
        }
    }
    __syncthreads();
    float wv = w[tid], bv = bsc[tid];
    #pragma unroll
    for (int r = 0; r < L_TOK; r++)
        xs[r * D + tid] = (xr[r * D + tid] - rowm[r]) * rowrs[r] * wv + bv;
    __syncthreads();
}

__global__ __launch_bounds__(256) void transformer_kernel(
    const float* __restrict__ tokens, const float* __restrict__ biasG,
    const float* __restrict__ in_w, const float* __restrict__ in_b,
    const float* __restrict__ out_w, const float* __restrict__ out_b,
    const float* __restrict__ l1w, const float* __restrict__ l1b,
    const float* __restrict__ l2w, const float* __restrict__ l2b,
    const float* __restrict__ ln1w, const float* __restrict__ ln1b,
    const float* __restrict__ ln2w, const float* __restrict__ ln2b,
    const float* __restrict__ c1w, const float* __restrict__ c1b,
    const float* __restrict__ c2w, const float* __restrict__ c2b,
    float* __restrict__ out)
{
    int b = blockIdx.x;
    int tid = threadIdx.x;

    __shared__ float xs[L_TOK * D];       // 2560: current x
    __shared__ float qkvS[L_TOK * 768];   // 7680: qkv; reused as residual buffer xr
    __shared__ float tmpS[L_TOK * FF];    // 5120: ao[0..2560) / sc[2560..3360) / ff hidden / ct / hbuf
    __shared__ float biasK[16];
    __shared__ float rowst[20];           // [0..10) mean, [10..20) rstd

    float* xr = qkvS;
    float* ao = tmpS;
    float* sc = tmpS + 2560;
    float* h1 = tmpS;
    float* ct = tmpS;
    float* hbuf = tmpS + 1024;

    for (int i = tid; i < L_TOK * D; i += 256) xs[i] = tokens[(size_t)b * L_TOK * D + i];
    if (tid < L_TOK) biasK[tid] = biasG[b * L_TOK + tid];
    __syncthreads();

    for (int l = 0; l < NLAYERS; l++) {
        // ---- QKV projection: qkv[r][c] = x[r] . in_w[l][c] + in_b[l][c]
        {
            float acc[3][L_TOK];
            #pragma unroll
            for (int j = 0; j < 3; j++)
                #pragma unroll
                for (int r = 0; r < L_TOK; r++) acc[j][r] = 0.f;
            const float4* w0 = reinterpret_cast<const float4*>(in_w + ((size_t)l * 768 + tid) * D);
            const float4* w1 = reinterpret_cast<const float4*>(in_w + ((size_t)l * 768 + tid + 256) * D);
            const float4* w2 = reinterpret_cast<const float4*>(in_w + ((size_t)l * 768 + tid + 512) * D);
            for (int k4 = 0; k4 < D / 4; k4++) {
                float4 a0 = w0[k4], a1 = w1[k4], a2 = w2[k4];
                int k = k4 * 4;
                #pragma unroll
                for (int r = 0; r < L_TOK; r++) {
                    float x0 = xs[r * D + k], x1 = xs[r * D + k + 1];
                    float x2 = xs[r * D + k + 2], x3 = xs[r * D + k + 3];
                    acc[0][r] += a0.x * x0 + a0.y * x1 + a0.z * x2 + a0.w * x3;
                    acc[1][r] += a1.x * x0 + a1.y * x1 + a1.z * x2 + a1.w * x3;
                    acc[2][r] += a2.x * x0 + a2.y * x1 + a2.z * x2 + a2.w * x3;
                }
            }
            #pragma unroll
            for (int j = 0; j < 3; j++) {
                int c = tid + j * 256;
                float bb = in_b[l * 768 + c];
                #pragma unroll
                for (int r = 0; r < L_TOK; r++) qkvS[r * 768 + c] = acc[j][r] + bb;
            }
        }
        __syncthreads();

        // ---- attention scores + bias
        const float scale = 0.17677669529663687f;  // 1/sqrt(32)
        for (int t = tid; t < NHEAD * L_TOK * L_TOK; t += 256) {
            int h = t / (L_TOK * L_TOK);
            int rem = t - h * (L_TOK * L_TOK);
            int qr = rem / L_TOK;
            int kr = rem - qr * L_TOK;
            const float* qp = &qkvS[qr * 768 + h * DHEAD];
            const float* kp = &qkvS[kr * 768 + 256 + h * DHEAD];
            float s = 0.f;
            #pragma unroll
            for (int dh = 0; dh < DHEAD; dh++) s += qp[dh] * kp[dh];
            sc[t] = s * scale + biasK[kr];
        }
        __syncthreads();

        // ---- softmax over keys, one thread per (h, qr) row
        if (tid < NHEAD * L_TOK) {
            float* row = &sc[tid * L_TOK];
            float m = row[0];
            #pragma unroll
            for (int k = 1; k < L_TOK; k++) m = fmaxf(m, row[k]);
            float ssum = 0.f;
            #pragma unroll
            for (int k = 0; k < L_TOK; k++) { float e = expf(row[k] - m); row[k] = e; ssum += e; }
            float inv = 1.f / ssum;
            #pragma unroll
            for (int k = 0; k < L_TOK; k++) row[k] *= inv;
        }
        __syncthreads();

        // ---- attn @ V -> ao[r][c]
        {
            int c = tid, h = c >> 5;
            #pragma unroll
            for (int r = 0; r < L_TOK; r++) {
                float s = 0.f;
                #pragma unroll
                for (int kr = 0; kr < L_TOK; kr++)
                    s += sc[h * 100 + r * L_TOK + kr] * qkvS[kr * 768 + 512 + c];
                ao[r * D + c] = s;
            }
        }
        __syncthreads();

        // ---- out_proj + residual -> xr (reuses qkv buffer)
        {
            float acc[L_TOK];
            #pragma unroll
            for (int r = 0; r < L_TOK; r++) acc[r] = 0.f;
            const float4* w4 = reinterpret_cast<const float4*>(out_w + ((size_t)l * D + tid) * D);
            for (int k4 = 0; k4 < D / 4; k4++) {
                float4 wv = w4[k4];
                int k = k4 * 4;
                #pragma unroll
                for (int r = 0; r < L_TOK; r++)
                    acc[r] += wv.x * ao[r * D + k] + wv.y * ao[r * D + k + 1]
                            + wv.z * ao[r * D + k + 2] + wv.w * ao[r * D + k + 3];
            }
            float bb = out_b[l * D + tid];
            __syncthreads();  // done reading ao before anyone... (xr aliases qkv, ao in tmp; safe)
            #pragma unroll
            for (int r = 0; r < L_TOK; r++)
                xr[r * D + tid] = xs[r * D + tid] + acc[r] + bb;
        }
        __syncthreads();
        layer_norm_10x256(xr, xs, ln1w + l * D, ln1b + l * D, rowst, rowst + 10, tid);

        // ---- FF1: h1[r][f] = relu(x[r] . l1w[l][f] + b), f = tid, tid+256
        {
            float acc[2][L_TOK];
            #pragma unroll
            for (int j = 0; j < 2; j++)
                #pragma unroll
                for (int r = 0; r < L_TOK; r++) acc[j][r] = 0.f;
            const float4* w0 = reinterpret_cast<const float4*>(l1w + ((size_t)l * FF + tid) * D);
            const float4* w1 = reinterpret_cast<const float4*>(l1w + ((size_t)l * FF + tid + 256) * D);
            for (int k4 = 0; k4 < D / 4; k4++) {
                float4 a0 = w0[k4], a1 = w1[k4];
                int k = k4 * 4;
                #pragma unroll
                for (int r = 0; r < L_TOK; r++) {
                    float x0 = xs[r * D + k], x1 = xs[r * D + k + 1];
                    float x2 = xs[r * D + k + 2], x3 = xs[r * D + k + 3];
                    acc[0][r] += a0.x * x0 + a0.y * x1 + a0.z * x2 + a0.w * x3;
                    acc[1][r] += a1.x * x0 + a1.y * x1 + a1.z * x2 + a1.w * x3;
                }
            }
            __syncthreads();  // tmp (sc region etc.) dead; safe to overwrite as h1
            #pragma unroll
            for (int j = 0; j < 2; j++) {
                int f = tid + j * 256;
                float bb = l1b[l * FF + f];
                #pragma unroll
                for (int r = 0; r < L_TOK; r++)
                    h1[r * FF + f] = fmaxf(acc[j][r] + bb, 0.f);
            }
        }
        __syncthreads();

        // ---- FF2 + residual -> xr
        {
            float acc[L_TOK];
            #pragma unroll
            for (int r = 0; r < L_TOK; r++) acc[r] = 0.f;
            const float4* w4 = reinterpret_cast<const float4*>(l2w + ((size_t)l * D + tid) * FF);
            for (int k4 = 0; k4 < FF / 4; k4++) {
                float4 wv = w4[k4];
                int k = k4 * 4;
                #pragma unroll
                for (int r = 0; r < L_TOK; r++)
                    acc[r] += wv.x * h1[r * FF + k] + wv.y * h1[r * FF + k + 1]
                            + wv.z * h1[r * FF + k + 2] + wv.w * h1[r * FF + k + 3];
            }
            float bb = l2b[l * D + tid];
            #pragma unroll
            for (int r = 0; r < L_TOK; r++)
                xr[r * D + tid] = xs[r * D + tid] + acc[r] + bb;
        }
        __syncthreads();
        layer_norm_10x256(xr, xs, ln2w + l * D, ln2b + l * D, rowst, rowst + 10, tid);
    }

    // ---- masked mean pool over valid tokens
    {
        float len = 0.f;
        float s = 0.f;
        #pragma unroll
        for (int r = 0; r < L_TOK; r++) {
            float v = (biasK[r] == 0.f) ? 1.f : 0.f;
            len += v;
            s += v * xs[r * D + tid];
        }
        len = fmaxf(len, 1.f);
        ct[tid] = s / len;
    }
    __syncthreads();

    // ---- classifier layer 1 (relu), outputs tid and tid+256
    {
        float acc0 = 0.f, acc1 = 0.f;
        const float4* w0 = reinterpret_cast<const float4*>(c1w + (size_t)tid * D);
        const float4* w1 = reinterpret_cast<const float4*>(c1w + (size_t)(tid + 256) * D);
        for (int k4 = 0; k4 < D / 4; k4++) {
            float4 a0 = w0[k4], a1 = w1[k4];
            int k = k4 * 4;
            float x0 = ct[k], x1 = ct[k + 1], x2 = ct[k + 2], x3 = ct[k + 3];
            acc0 += a0.x * x0 + a0.y * x1 + a0.z * x2 + a0.w * x3;
            acc1 += a1.x * x0 + a1.y * x1 + a1.z * x2 + a1.w * x3;
        }
        __syncthreads();  // ct fully read before hbuf write (disjoint regions, but keep order)
        hbuf[tid] = fmaxf(acc0 + c1b[tid], 0.f);
        hbuf[tid + 256] = fmaxf(acc1 + c1b[tid + 256], 0.f);
    }
    __syncthreads();

    // ---- classifier layer 2 -> logits
    for (int o = tid; o < NCLS; o += 256) {
        const float4* w4 = reinterpret_cast<const float4*>(c2w + (size_t)o * FF);
        float acc = 0.f;
        for (int k4 = 0; k4 < FF / 4; k4++) {
            float4 wv = w4[k4];
            int k = k4 * 4;
            acc += wv.x * hbuf[k] + wv.y * hbuf[k + 1] + wv.z * hbuf[k + 2] + wv.w * hbuf[k + 3];
        }
        out[(size_t)b * NCLS + o] = acc + c2b[o];
    }
}

// ---------------------------------------------------------------------------
extern "C" void kernel_launch(void* const* d_in, const int* in_sizes, int n_in,
                              void* d_out, int out_size, void* d_ws, size_t ws_size,
                              hipStream_t stream)
{
    const float* pred = (const float*)d_in[0];
    const float* hs   = (const float*)d_in[1];
    const float* f0   = (const float*)d_in[2];
    const float* f1   = (const float*)d_in[3];
    const float* f2   = (const float*)d_in[4];
    const float* f3   = (const float*)d_in[5];
    const float* ipw  = (const float*)d_in[6];
    const float* ipb  = (const float*)d_in[7];
    const float* inw  = (const float*)d_in[8];
    const float* inb  = (const float*)d_in[9];
    const float* ow   = (const float*)d_in[10];
    const float* ob   = (const float*)d_in[11];
    const float* l1w  = (const float*)d_in[12];
    const float* l1b  = (const float*)d_in[13];
    const float* l2w  = (const float*)d_in[14];
    const float* l2b  = (const float*)d_in[15];
    const float* ln1w = (const float*)d_in[16];
    const float* ln1b = (const float*)d_in[17];
    const float* ln2w = (const float*)d_in[18];
    const float* ln2b = (const float*)d_in[19];
    const float* c1w  = (const float*)d_in[20];
    const float* c1b  = (const float*)d_in[21];
    const float* c2w  = (const float*)d_in[22];
    const float* c2b  = (const float*)d_in[23];

    float* ws = (float*)d_ws;
    float* pooled = ws;                       // B*4*D   = 65536
    float* tokens = pooled + B * 4 * D;       // B*10*D  = 163840
    float* biasL  = tokens + B * L_TOK * D;   // B*10    = 640

    pool_kernel<<<4 * B * D / 1, 256, 0, stream>>>(f0, f1, f2, f3, pooled);
    img_proj_kernel<<<B * 4, 256, 0, stream>>>(pooled, ipw, ipb, tokens);
    cls_pool_kernel<<<B, 256, 0, stream>>>(pred, hs, tokens, biasL);
    transformer_kernel<<<B, 256, 0, stream>>>(
        tokens, biasL, inw, inb, ow, ob, l1w, l1b, l2w, l2b,
        ln1w, ln1b, ln2w, ln2b, c1w, c1b, c2w, c2b, (float*)d_out);
}